// Round 6
// baseline (262.871 us; speedup 1.0000x reference)
//
#include <hip/hip_runtime.h>
#include <math.h>

// Problem: B=262144, IN_DIM=2, OUT_DIM=256
// out[0 .. B*256)   = cos(x @ h^T + delta)   (row-major [B,256], f32)
// out[B*256]        = sum_o atan2(mean_b sin, mean_b cos) / pi
//
// Decomposition: dur_us includes ~204.5us of harness poison fills (1 GiB ws
// + 268 MB out @ ~6.5 TB/s). Kernel budget ~55us vs ~50us floor
// (41.0us main stores @6.55 TB/s + 3 launches/gaps + fin).
// R6 (atomic-slot + separate fin): 270.5. R7-R9 (fused finisher): FAILED —
// per-block device-scope fences emit L2 writeback/inv -> 6x main blowup.
// Fences in a streaming-store kernel are catastrophic; kernel-boundary
// ordering is free. R10 (plain stores, not NT): 259.9 (-10.6us) — NT was
// costing ~20% of store BW. BEST=R10.
// R11: epilogue micro-levers. (1) NSLOT 8->32: atomic tail 256->64
// serialized adds/address. (2) unroll 4->8: more independent sincos/store
// chains (VGPR=32, headroom). Store loop structure unchanged.

#define B_DIM 262144
#define O_DIM 256
#define NB1 2048   // main blocks: 256 CUs x 8 blocks/CU, one dispatch wave
#define ROWS_PER_BLOCK (B_DIM / NB1)        // 128
#define ROWS_PER_WAVE (ROWS_PER_BLOCK / 4)  // 32
#define NSLOT 32   // atomic accumulator slots: acc[NSLOT][512]

typedef float vf4 __attribute__((ext_vector_type(4)));

// Zero the poisoned accumulator: NSLOT*512 floats = 64 KB. ws is poisoned
// every iteration, so this must run every launch.
__global__ __launch_bounds__(256) void fdc_init(float* __restrict__ acc) {
  acc[(size_t)blockIdx.x * 256 + threadIdx.x] = 0.f;
}

__global__ __launch_bounds__(256) void fdc_main(
    const float* __restrict__ x, const float* __restrict__ h,
    const float* __restrict__ delta, float* __restrict__ out,
    float* __restrict__ acc /* [NSLOT][512] */) {
  const int tid  = threadIdx.x;
  const int lane = tid & 63;   // group of 4 columns
  const int wv   = tid >> 6;   // wave 0..3
  const int col4 = lane * 4;

  // h is [256][2] row-major: cols col4..col4+3 occupy 8 consecutive floats.
  const float4* h4 = (const float4*)h;
  const float4 ha = h4[lane * 2];
  const float4 hb = h4[lane * 2 + 1];
  const float4 dl = ((const float4*)delta)[lane];

  // Stage this block's x rows (128 rows x float2 = 256 floats) via one
  // coalesced load -> no global-load latency inside the store loop.
  __shared__ float2 xs[ROWS_PER_BLOCK];
  ((float*)xs)[tid] = x[(size_t)blockIdx.x * (ROWS_PER_BLOCK * 2) + tid];
  __syncthreads();

  vf4* out4 = (vf4*)out;
  float sc0 = 0.f, sc1 = 0.f, sc2 = 0.f, sc3 = 0.f;
  float ss0 = 0.f, ss1 = 0.f, ss2 = 0.f, ss3 = 0.f;

  const int rbase = blockIdx.x * ROWS_PER_BLOCK + wv * ROWS_PER_WAVE;
  const int lbase = wv * ROWS_PER_WAVE;
#pragma unroll 8
  for (int i = 0; i < ROWS_PER_WAVE; ++i) {
    const float2 xv = xs[lbase + i];   // LDS broadcast, conflict-free
    const int row = rbase + i;
    float s, c;
    vf4 o;
    const float t0 = fmaf(xv.x, ha.x, fmaf(xv.y, ha.y, dl.x));
    const float t1 = fmaf(xv.x, ha.z, fmaf(xv.y, ha.w, dl.y));
    const float t2 = fmaf(xv.x, hb.x, fmaf(xv.y, hb.y, dl.z));
    const float t3 = fmaf(xv.x, hb.z, fmaf(xv.y, hb.w, dl.w));
    __sincosf(t0, &s, &c); o.x = c; sc0 += c; ss0 += s;
    __sincosf(t1, &s, &c); o.y = c; sc1 += c; ss1 += s;
    __sincosf(t2, &s, &c); o.z = c; sc2 += c; ss2 += s;
    __sincosf(t3, &s, &c); o.w = c; sc3 += c; ss3 += s;
    out4[(size_t)row * 64 + lane] = o;   // plain store (R10: beats NT)
  }

  // Reduce the 4 waves' column sums -> block column sums.
  __shared__ float lds[4][512];
  lds[wv][col4 + 0] = sc0; lds[wv][col4 + 1] = sc1;
  lds[wv][col4 + 2] = sc2; lds[wv][col4 + 3] = sc3;
  lds[wv][256 + col4 + 0] = ss0; lds[wv][256 + col4 + 1] = ss1;
  lds[wv][256 + col4 + 2] = ss2; lds[wv][256 + col4 + 3] = ss3;
  __syncthreads();
  const float a = lds[0][tid] + lds[1][tid] + lds[2][tid] + lds[3][tid];
  const float b = lds[0][tid + 256] + lds[1][tid + 256] +
                  lds[2][tid + 256] + lds[3][tid + 256];

  // Global accumulation: 32 slots -> NB1/NSLOT = 64 adds per address,
  // issued staggered as blocks drain. atomicAdd is device-scope by
  // default (cross-XCD safe, learn_hip m20). NO fences here — the
  // kernel boundary before fdc_fin provides ordering for free.
  float* slot = acc + (size_t)(blockIdx.x & (NSLOT - 1)) * 512;
  atomicAdd(slot + tid, a);         // cos sums, cols 0..255
  atomicAdd(slot + 256 + tid, b);   // sin sums
}

// Finisher: fold NSLOT slots (64 KB, fully unrolled independent loads ->
// ~2 latency rounds), atan2 per column, LDS-reduce 256 angles -> eta.
// Kernel-boundary on the stream guarantees visibility of the atomics.
__global__ __launch_bounds__(256) void fdc_fin(
    const float* __restrict__ acc, float* __restrict__ out) {
  const int t = threadIdx.x;
  float cs = 0.f, sn = 0.f;
#pragma unroll
  for (int r = 0; r < NSLOT; ++r) {
    cs += acc[(size_t)r * 512 + t];
    sn += acc[(size_t)r * 512 + 256 + t];
  }
  float ang = atan2f(sn, cs);  // 1/B scale cancels in atan2
  __shared__ float red[256];
  red[t] = ang;
  __syncthreads();
  for (int st = 128; st > 0; st >>= 1) {
    if (t < st) red[t] += red[t + st];
    __syncthreads();
  }
  if (t == 0) out[(size_t)B_DIM * O_DIM] = red[0] * (float)(1.0 / M_PI);
}

extern "C" void kernel_launch(void* const* d_in, const int* in_sizes, int n_in,
                              void* d_out, int out_size, void* d_ws, size_t ws_size,
                              hipStream_t stream) {
  const float* x     = (const float*)d_in[0];
  const float* h     = (const float*)d_in[1];
  const float* delta = (const float*)d_in[2];
  float* out = (float*)d_out;
  float* acc = (float*)d_ws;   // NSLOT*512 floats = 64 KB (ws poisoned -> init)
  (void)ws_size;

  fdc_init<<<NSLOT * 2, 256, 0, stream>>>(acc);
  fdc_main<<<NB1, 256, 0, stream>>>(x, h, delta, out, acc);
  fdc_fin<<<1, 256, 0, stream>>>(acc, out);
}

// Round 7
// 259.819 us; speedup vs baseline: 1.0117x; 1.0117x over previous
//
#include <hip/hip_runtime.h>
#include <math.h>

// Problem: B=262144, IN_DIM=2, OUT_DIM=256
// out[0 .. B*256)   = cos(x @ h^T + delta)   (row-major [B,256], f32)
// out[B*256]        = sum_o atan2(mean_b sin, mean_b cos) / pi
//
// Decomposition: dur_us includes ~204.5us of harness poison fills (1 GiB ws
// + 268 MB out @ ~6.5 TB/s). Kernel budget ~55us vs ~50us floor
// (41.0us main stores @6.55 TB/s + 3 launches/gaps + fin).
// History: R6 (atomic-slot + separate fin) 270.5. R7-R9 (fused last-block
// finisher) FAILED — per-block device-scope fences emit L2 writeback/inv
// -> 1.4 GB FETCH, main 50->323us. Fences in a streaming-store kernel are
// catastrophic; kernel-boundary ordering is free. R10 (plain stores, not
// NT) 259.9 — NT cost ~20% of store BW. R11 (NSLOT 32 + unroll 8) 262.9
// REGRESSION — deeper unroll lengthens register-live store bursts.
// R12: revert verbatim to R10, the best measured artifact. Remaining
// headroom (~5us) is at the fill-noise floor (+/-3us); no lever left that
// clears it. This is the closing configuration.

#define B_DIM 262144
#define O_DIM 256
#define NB1 2048   // main blocks: 256 CUs x 8 blocks/CU, one dispatch wave
#define ROWS_PER_BLOCK (B_DIM / NB1)        // 128
#define ROWS_PER_WAVE (ROWS_PER_BLOCK / 4)  // 32
#define NSLOT 8    // atomic accumulator slots: acc[NSLOT][512]

typedef float vf4 __attribute__((ext_vector_type(4)));

// Zero the poisoned accumulator: NSLOT*512 floats = 16 KB. ws is poisoned
// every iteration, so this must run every launch.
__global__ __launch_bounds__(256) void fdc_init(float* __restrict__ acc) {
  acc[(size_t)blockIdx.x * 256 + threadIdx.x] = 0.f;
}

__global__ __launch_bounds__(256) void fdc_main(
    const float* __restrict__ x, const float* __restrict__ h,
    const float* __restrict__ delta, float* __restrict__ out,
    float* __restrict__ acc /* [NSLOT][512] */) {
  const int tid  = threadIdx.x;
  const int lane = tid & 63;   // group of 4 columns
  const int wv   = tid >> 6;   // wave 0..3
  const int col4 = lane * 4;

  // h is [256][2] row-major: cols col4..col4+3 occupy 8 consecutive floats.
  const float4* h4 = (const float4*)h;
  const float4 ha = h4[lane * 2];
  const float4 hb = h4[lane * 2 + 1];
  const float4 dl = ((const float4*)delta)[lane];

  // Stage this block's x rows (128 rows x float2 = 256 floats) via one
  // coalesced load -> no global-load latency inside the store loop.
  __shared__ float2 xs[ROWS_PER_BLOCK];
  ((float*)xs)[tid] = x[(size_t)blockIdx.x * (ROWS_PER_BLOCK * 2) + tid];
  __syncthreads();

  vf4* out4 = (vf4*)out;
  float sc0 = 0.f, sc1 = 0.f, sc2 = 0.f, sc3 = 0.f;
  float ss0 = 0.f, ss1 = 0.f, ss2 = 0.f, ss3 = 0.f;

  const int rbase = blockIdx.x * ROWS_PER_BLOCK + wv * ROWS_PER_WAVE;
  const int lbase = wv * ROWS_PER_WAVE;
#pragma unroll 4
  for (int i = 0; i < ROWS_PER_WAVE; ++i) {
    const float2 xv = xs[lbase + i];   // LDS broadcast, conflict-free
    const int row = rbase + i;
    float s, c;
    vf4 o;
    const float t0 = fmaf(xv.x, ha.x, fmaf(xv.y, ha.y, dl.x));
    const float t1 = fmaf(xv.x, ha.z, fmaf(xv.y, ha.w, dl.y));
    const float t2 = fmaf(xv.x, hb.x, fmaf(xv.y, hb.y, dl.z));
    const float t3 = fmaf(xv.x, hb.z, fmaf(xv.y, hb.w, dl.w));
    __sincosf(t0, &s, &c); o.x = c; sc0 += c; ss0 += s;
    __sincosf(t1, &s, &c); o.y = c; sc1 += c; ss1 += s;
    __sincosf(t2, &s, &c); o.z = c; sc2 += c; ss2 += s;
    __sincosf(t3, &s, &c); o.w = c; sc3 += c; ss3 += s;
    out4[(size_t)row * 64 + lane] = o;   // plain store (R10: beats NT)
  }

  // Reduce the 4 waves' column sums -> block column sums.
  __shared__ float lds[4][512];
  lds[wv][col4 + 0] = sc0; lds[wv][col4 + 1] = sc1;
  lds[wv][col4 + 2] = sc2; lds[wv][col4 + 3] = sc3;
  lds[wv][256 + col4 + 0] = ss0; lds[wv][256 + col4 + 1] = ss1;
  lds[wv][256 + col4 + 2] = ss2; lds[wv][256 + col4 + 3] = ss3;
  __syncthreads();
  const float a = lds[0][tid] + lds[1][tid] + lds[2][tid] + lds[3][tid];
  const float b = lds[0][tid + 256] + lds[1][tid + 256] +
                  lds[2][tid + 256] + lds[3][tid + 256];

  // Global accumulation: 8 slots -> NB1/NSLOT = 256 adds per address,
  // issued staggered as blocks drain. atomicAdd is device-scope by
  // default (cross-XCD safe, learn_hip m20). NO fences here — the
  // kernel boundary before fdc_fin provides ordering for free.
  float* slot = acc + (size_t)(blockIdx.x & (NSLOT - 1)) * 512;
  atomicAdd(slot + tid, a);         // cos sums, cols 0..255
  atomicAdd(slot + 256 + tid, b);   // sin sums
}

// Finisher: fold NSLOT slots (16 KB, fully unrolled independent loads ->
// one latency round), atan2 per column, LDS-reduce 256 angles -> eta.
// Kernel-boundary on the stream guarantees visibility of the atomics.
__global__ __launch_bounds__(256) void fdc_fin(
    const float* __restrict__ acc, float* __restrict__ out) {
  const int t = threadIdx.x;
  float cs = 0.f, sn = 0.f;
#pragma unroll
  for (int r = 0; r < NSLOT; ++r) {
    cs += acc[(size_t)r * 512 + t];
    sn += acc[(size_t)r * 512 + 256 + t];
  }
  float ang = atan2f(sn, cs);  // 1/B scale cancels in atan2
  __shared__ float red[256];
  red[t] = ang;
  __syncthreads();
  for (int st = 128; st > 0; st >>= 1) {
    if (t < st) red[t] += red[t + st];
    __syncthreads();
  }
  if (t == 0) out[(size_t)B_DIM * O_DIM] = red[0] * (float)(1.0 / M_PI);
}

extern "C" void kernel_launch(void* const* d_in, const int* in_sizes, int n_in,
                              void* d_out, int out_size, void* d_ws, size_t ws_size,
                              hipStream_t stream) {
  const float* x     = (const float*)d_in[0];
  const float* h     = (const float*)d_in[1];
  const float* delta = (const float*)d_in[2];
  float* out = (float*)d_out;
  float* acc = (float*)d_ws;   // NSLOT*512 floats = 16 KB (ws poisoned -> init)
  (void)ws_size;

  fdc_init<<<NSLOT * 2, 256, 0, stream>>>(acc);
  fdc_main<<<NB1, 256, 0, stream>>>(x, h, delta, out, acc);
  fdc_fin<<<1, 256, 0, stream>>>(acc, out);
}